// Round 7
// baseline (479.577 us; speedup 1.0000x reference)
//
#include <hip/hip_runtime.h>
#include <hip/hip_bf16.h>
#include <math.h>

// Problem constants
#define BB 4
#define TT 1024
#define DIM 1024
#define HEADS 16
#define DH 64
#define INNER 1024
#define MLP 4096

// mod chunk offsets (per batch row of 6*DIM)
#define OFF_SH_MSA 0
#define OFF_SC_MSA 1024
#define OFF_G_MSA  2048
#define OFF_SH_MLP 3072
#define OFF_SC_MLP 4096
#define OFF_G_MLP  5120

typedef __attribute__((ext_vector_type(8))) short bf16x8;   // 8 bf16 in 4 VGPRs
typedef __attribute__((ext_vector_type(4))) float fx4;      // MFMA accumulator

__device__ __forceinline__ unsigned short f2bf(float f) {
    __hip_bfloat16 h = __float2bfloat16(f);   // RNE
    return __builtin_bit_cast(unsigned short, h);
}

__device__ __forceinline__ void gload_lds16(const void* g, void* l) {
    __builtin_amdgcn_global_load_lds((const __attribute__((address_space(1))) void*)g,
                                     (__attribute__((address_space(3))) void*)l, 16, 0, 0);
}

// ---------------------------------------------------------------------------
// Kernel 1a/1b: modulation GEMM (k-split) + reduce
// ---------------------------------------------------------------------------
__global__ __launch_bounds__(256) void mod_partial(
    const float* __restrict__ c, const float* __restrict__ W_mod,
    float* __restrict__ part)
{
    __shared__ float sc[BB][128];
    int tid = threadIdx.x;
    int ks = blockIdx.y;
    int k0 = ks * 128;
    for (int i = tid; i < BB * 128; i += 256) {
        int bq = i >> 7, kk = i & 127;
        float v = c[bq * 1024 + k0 + kk];
        sc[bq][kk] = v / (1.0f + __expf(-v));
    }
    __syncthreads();
    int n = blockIdx.x * 256 + tid;   // 0..6143
    float a0 = 0.f, a1 = 0.f, a2 = 0.f, a3 = 0.f;
    for (int kk = 0; kk < 128; kk++) {
        float w = W_mod[(size_t)(k0 + kk) * 6144 + n];
        a0 += sc[0][kk] * w;
        a1 += sc[1][kk] * w;
        a2 += sc[2][kk] * w;
        a3 += sc[3][kk] * w;
    }
    float* p = part + (size_t)ks * 4 * 6144 + n;
    p[0]        = a0;
    p[6144]     = a1;
    p[2 * 6144] = a2;
    p[3 * 6144] = a3;
}

__global__ __launch_bounds__(256) void mod_reduce(
    const float* __restrict__ part, const float* __restrict__ b_mod,
    float* __restrict__ mod)
{
    int n = blockIdx.x * 256 + threadIdx.x;
    float bb = b_mod[n];
    #pragma unroll
    for (int bq = 0; bq < 4; bq++) {
        float a = bb;
        #pragma unroll
        for (int ks = 0; ks < 8; ks++) a += part[(size_t)(ks * 4 + bq) * 6144 + n];
        mod[bq * 6144 + n] = a;
    }
}

// ---------------------------------------------------------------------------
// Kernel 2: fused LayerNorm (affine-free) + modulate -> bf16
// ---------------------------------------------------------------------------
__global__ __launch_bounds__(256) void ln_mod_kernel(
    const float* __restrict__ x, const float* __restrict__ mod,
    int sh_off, int sc_off, unsigned short* __restrict__ out)
{
    int row = blockIdx.x;           // 0..B*T-1
    int b = row >> 10;              // T = 1024
    const float* xr = x + (size_t)row * DIM;
    float4 v = ((const float4*)xr)[threadIdx.x];

    float s1 = v.x + v.y + v.z + v.w;
    float s2 = v.x * v.x + v.y * v.y + v.z * v.z + v.w * v.w;
    #pragma unroll
    for (int off = 32; off > 0; off >>= 1) {
        s1 += __shfl_down(s1, off, 64);
        s2 += __shfl_down(s2, off, 64);
    }
    __shared__ float red[8];
    int lane = threadIdx.x & 63, w = threadIdx.x >> 6;
    if (lane == 0) { red[w] = s1; red[4 + w] = s2; }
    __syncthreads();
    s1 = red[0] + red[1] + red[2] + red[3];
    s2 = red[4] + red[5] + red[6] + red[7];
    float mu = s1 * (1.0f / DIM);
    float var = s2 * (1.0f / DIM) - mu * mu;
    float rs = rsqrtf(var + 1e-5f);

    int col = threadIdx.x * 4;
    const float* mb = mod + (size_t)b * 6144;
    float4 sc4 = *(const float4*)(mb + sc_off + col);
    float4 sh4 = *(const float4*)(mb + sh_off + col);
    ushort4 o;
    o.x = f2bf((v.x - mu) * rs * (1.0f + sc4.x) + sh4.x);
    o.y = f2bf((v.y - mu) * rs * (1.0f + sc4.y) + sh4.y);
    o.z = f2bf((v.z - mu) * rs * (1.0f + sc4.z) + sh4.z);
    o.w = f2bf((v.w - mu) * rs * (1.0f + sc4.w) + sh4.w);
    ((ushort4*)(out + (size_t)row * DIM))[threadIdx.x] = o;
}

// ---------------------------------------------------------------------------
// Kernel 3: fused weight transpose+convert (one dispatch, 12288 tiles)
// ---------------------------------------------------------------------------
__global__ __launch_bounds__(256) void wcvt_all(
    const float* __restrict__ Wqkv, const float* __restrict__ Wout,
    const float* __restrict__ W1,   const float* __restrict__ W2,
    unsigned short* __restrict__ oQ, unsigned short* __restrict__ oO,
    unsigned short* __restrict__ o1, unsigned short* __restrict__ o2)
{
    __shared__ float tile[32][33];
    int t = blockIdx.x;
    const float* W; unsigned short* O; int K, N, nx;
    if (t < 3072)      {            W = Wqkv; O = oQ; K = 1024; N = 3072; nx = 96;  }
    else if (t < 4096) { t -= 3072; W = Wout; O = oO; K = 1024; N = 1024; nx = 32;  }
    else if (t < 8192) { t -= 4096; W = W1;   O = o1; K = 1024; N = 4096; nx = 128; }
    else               { t -= 8192; W = W2;   O = o2; K = 4096; N = 1024; nx = 32;  }
    int n0 = (t % nx) * 32, k0 = (t / nx) * 32;
    int tx = threadIdx.x & 31, ty = threadIdx.x >> 5;   // 32 x 8
    #pragma unroll
    for (int i = 0; i < 4; i++)
        tile[ty + i * 8][tx] = W[(size_t)(k0 + ty + i * 8) * N + n0 + tx];
    __syncthreads();
    #pragma unroll
    for (int i = 0; i < 4; i++)
        O[(size_t)(n0 + ty + i * 8) * K + k0 + tx] = f2bf(tile[tx][ty + i * 8]);
}

// ---------------------------------------------------------------------------
// Kernel 4: 256x256 pipelined bf16 MFMA GEMM (T3/T4 mechanics).
// 512 threads = 8 waves (2 row x 4 col), wave tile 128x64, BK=32.
// LDS: 4 buffers x (A 16KB + B 16KB) = 128KB. Prefetch depth 3.
// One raw s_barrier per K-tile; counted vmcnt(8) in steady state (loads for
// 2 future tiles stay in flight across barriers); tail peels 8->4->0.
// LDS rows (32 bf16 = 4 x 16B slots) swizzled: phys_slot = slot ^ (row&3),
// applied on the pre-swizzled global SOURCE (G21) and on reads -> b128 reads
// hit the conflict-free floor.
// EPI: 0 none(bf16) / 1 bias+gelu(bf16) / 2 res+gate(f32) / 3 raw f32 partial
// Grid z: split-K slices (A/Bt advanced by z*kz, Cout by z*zout elements).
// ---------------------------------------------------------------------------
template<int EPI, int OBF>
__global__ __launch_bounds__(512, 2) void bgemm256(
    const unsigned short* __restrict__ A0, const unsigned short* __restrict__ Bt0,
    const float* __restrict__ bias, const float* __restrict__ res,
    const float* __restrict__ mod, int gate_off,
    void* __restrict__ Cout, int M, int N, int Klen, int lda, int ldb,
    int kz, int zout)
{
    __shared__ unsigned short As[4][8192];   // [buf][256 rows x 32 k]
    __shared__ unsigned short Bs[4][8192];

    const int tid = threadIdx.x;
    const int lane = tid & 63, wid = tid >> 6;
    const int rl = lane & 15, lg = lane >> 4;     // frag row / k-group
    const int rl4 = rl & 3;
    const int wr = wid >> 2, wc = wid & 3;        // 2x4 wave grid

    // XCD chunked swizzle on (x,y); z = split-K slice
    const int gx = gridDim.x;
    const int nwg = gx * gridDim.y;
    const int bid = blockIdx.y * gx + blockIdx.x;
    const int swz = (bid & 7) * (nwg >> 3) + (bid >> 3);
    const int row0 = (swz / gx) * 256;
    const int col0 = (swz % gx) * 256;

    const unsigned short* A  = A0  + (size_t)blockIdx.z * kz;
    const unsigned short* Bt = Bt0 + (size_t)blockIdx.z * kz;

    // staging geometry: per round, thread covers row rA (+128 for round 1),
    // physical 16B slot pA; source slot s = pA ^ (rA&3)  (swizzle inverse)
    const int rA = tid >> 2;               // 0..127
    const int pA = tid & 3;
    const int sA = (pA ^ (rA & 3)) * 8;    // source element offset in row
    const unsigned short* a0p = A  + (size_t)(row0 + rA) * lda + sA;
    const unsigned short* a1p = A  + (size_t)(row0 + 128 + rA) * lda + sA;
    const unsigned short* b0p = Bt + (size_t)(col0 + rA) * ldb + sA;
    const unsigned short* b1p = Bt + (size_t)(col0 + 128 + rA) * ldb + sA;

    fx4 acc[8][4];
    const fx4 zero = {0.f, 0.f, 0.f, 0.f};
    #pragma unroll
    for (int m = 0; m < 8; m++)
        #pragma unroll
        for (int n = 0; n < 4; n++) acc[m][n] = zero;

    const int NT = Klen >> 5;   // K-tiles of 32 (NT >= 32 for all call sites)

#define STAGE256(q, kt) do {                                   \
        int koff = (kt) << 5;                                  \
        gload_lds16(a0p + koff, As[q] + tid * 8);              \
        gload_lds16(a1p + koff, As[q] + 4096 + tid * 8);       \
        gload_lds16(b0p + koff, Bs[q] + tid * 8);              \
        gload_lds16(b1p + koff, Bs[q] + 4096 + tid * 8);       \
    } while (0)

    // prologue: stage tiles 0,1,2 (12 vmem ops in flight)
    STAGE256(0, 0);
    STAGE256(1, 1);
    STAGE256(2, 2);

    const int ro = (lg ^ rl4) * 8;         // swizzled read slot offset
    for (int t = 0; t < NT; ++t) {
        // wait for tile t only (counted): steady 8 = tiles t+1,t+2 in flight
        if (t < NT - 2)       asm volatile("s_waitcnt vmcnt(8)" ::: "memory");
        else if (t == NT - 2) asm volatile("s_waitcnt vmcnt(4)" ::: "memory");
        else                  asm volatile("s_waitcnt vmcnt(0)" ::: "memory");
        __builtin_amdgcn_s_barrier();
        // issue prefetch of tile t+3 into the buffer freed at iter t-1
        if (t + 3 < NT) STAGE256((t + 3) & 3, t + 3);

        const int q = t & 3;
        bf16x8 bfr[4], af[8];
        #pragma unroll
        for (int n = 0; n < 4; n++)
            bfr[n] = *(const bf16x8*)(Bs[q] + (wc * 64 + n * 16 + rl) * 32 + ro);
        #pragma unroll
        for (int m = 0; m < 8; m++)
            af[m] = *(const bf16x8*)(As[q] + (wr * 128 + m * 16 + rl) * 32 + ro);
        __builtin_amdgcn_s_setprio(1);
        #pragma unroll
        for (int m = 0; m < 8; m++)
            #pragma unroll
            for (int n = 0; n < 4; n++)
                acc[m][n] = __builtin_amdgcn_mfma_f32_16x16x32_bf16(
                    af[m], bfr[n], acc[m][n], 0, 0, 0);
        __builtin_amdgcn_s_setprio(0);
    }
#undef STAGE256

    // epilogue; C/D map: col = rl, row = lg*4 + j  [verified]
    const int b = row0 >> 10;              // 256 | 1024: tile never crosses batch
    unsigned short* outb = (unsigned short*)Cout + (size_t)blockIdx.z * zout;
    float* outf = (float*)Cout + (size_t)blockIdx.z * zout;
    #pragma unroll
    for (int m = 0; m < 8; m++) {
        #pragma unroll
        for (int n = 0; n < 4; n++) {
            int col = col0 + wc * 64 + n * 16 + rl;
            float bv = 0.f, gate = 0.f;
            if (EPI == 1 || EPI == 2) bv = bias[col];
            if (EPI == 2) gate = mod[(size_t)b * 6144 + gate_off + col];
            #pragma unroll
            for (int j = 0; j < 4; j++) {
                int row = row0 + wr * 128 + m * 16 + lg * 4 + j;
                float v = acc[m][n][j];
                if (EPI == 1) {
                    float u = v + bv;
                    v = 0.5f * u * (1.0f + erff(u * 0.70710678118654752f));
                } else if (EPI == 2) {
                    v = res[(size_t)row * N + col] + gate * (v + bv);
                }
                if (OBF) outb[(size_t)row * N + col] = f2bf(v);
                else     outf[(size_t)row * N + col] = v;
            }
        }
    }
}

// ---------------------------------------------------------------------------
// Kernel 4b: FF2 finish: out = x1 + g_mlp * (b2 + part0 + part1)
// ---------------------------------------------------------------------------
__global__ __launch_bounds__(256) void ff2_fin(
    const float* __restrict__ part, const float* __restrict__ x1,
    const float* __restrict__ mod, const float* __restrict__ b2,
    float* __restrict__ out)
{
    int i = (blockIdx.x * 256 + threadIdx.x) * 4;   // 0..4M-1, row-contig
    int col = i & 1023;
    int b = i >> 20;
    float4 p0 = *(const float4*)(part + i);
    float4 p1 = *(const float4*)(part + 4194304 + i);
    float4 r  = *(const float4*)(x1 + i);
    float4 g  = *(const float4*)(mod + (size_t)b * 6144 + OFF_G_MLP + col);
    float4 bb = *(const float4*)(b2 + col);
    float4 o;
    o.x = r.x + g.x * (bb.x + p0.x + p1.x);
    o.y = r.y + g.y * (bb.y + p0.y + p1.y);
    o.z = r.z + g.z * (bb.z + p0.z + p1.z);
    o.w = r.w + g.w * (bb.w + p0.w + p1.w);
    *(float4*)(out + i) = o;
}

// ---------------------------------------------------------------------------
// Kernel 5: MFMA flash attention (verified) + XCD swizzle.
// ---------------------------------------------------------------------------
__global__ __launch_bounds__(256) void attn_mfma(
    const unsigned short* __restrict__ qkv, unsigned short* __restrict__ out)
{
    __shared__ unsigned short K_l[64 * 64];    // [kr][slot ^ (kr&7)]
    __shared__ unsigned short VT_l[64 * 64];   // [d][slot ^ (d&7) ^ ((d>>3)&7)]
    __shared__ unsigned short P_l[4 * 16 * 64];

    const int tid = threadIdx.x;
    const int lane = tid & 63, w = tid >> 6;
    const int rl = lane & 15, lg = lane >> 4;     // 0..15 / 0..3

    const int bid = blockIdx.x;                   // nwg = 1024
    const int swz = (bid & 7) * 128 + (bid >> 3);
    const int qi = swz & 15;
    const int bh = swz >> 4;
    const int b = bh >> 4, h = bh & 15;

    const unsigned short* base = qkv + (size_t)b * TT * 3 * INNER + h * DH;

    const int qrow = qi * 64 + w * 16 + rl;
    bf16x8 qf[2];
    qf[0] = *(const bf16x8*)(base + (size_t)qrow * 3 * INNER + lg * 8);
    qf[1] = *(const bf16x8*)(base + (size_t)qrow * 3 * INNER + lg * 8 + 32);

    const fx4 z4 = {0.f, 0.f, 0.f, 0.f};
    fx4 acc_o[4];
    #pragma unroll
    for (int db = 0; db < 4; db++) acc_o[db] = z4;
    float mrow[4] = {-INFINITY, -INFINITY, -INFINITY, -INFINITY};
    float lrow[4] = {0.f, 0.f, 0.f, 0.f};

    unsigned short* Pw = P_l + w * 1024;

    for (int kt = 0; kt < 16; kt++) {
        __syncthreads();
        #pragma unroll
        for (int i = 0; i < 2; i++) {
            int instr = w * 2 + i;
            int row = instr * 8 + (lane >> 3);
            int slog = (lane & 7) ^ (lane >> 3);      // logical 16B slot
            gload_lds16(base + (size_t)(kt * 64 + row) * 3 * INNER + INNER + slog * 8,
                        K_l + instr * 512);
        }
        #pragma unroll
        for (int hh = 0; hh < 2; hh++) {
            int dc = tid & 7;                    // d-chunk (8 d's)
            int kr = (tid >> 3) + hh * 32;       // k row
            const unsigned short* vg =
                base + (size_t)(kt * 64 + kr) * 3 * INNER + 2 * INNER + dc * 8;
            uint4 vv = *(const uint4*)vg;
            unsigned wds[4] = {vv.x, vv.y, vv.z, vv.w};
            #pragma unroll
            for (int j = 0; j < 8; j++) {
                unsigned word = wds[j >> 1];
                unsigned short e = (j & 1) ? (unsigned short)(word >> 16)
                                           : (unsigned short)(word & 0xffff);
                int d = dc * 8 + j;
                int phys = ((kr >> 3) ^ j ^ dc) & 7;
                VT_l[d * 64 + phys * 8 + (kr & 7)] = e;
            }
        }
        __syncthreads();

        fx4 sacc[4];
        #pragma unroll
        for (int kb = 0; kb < 4; kb++) sacc[kb] = z4;
        #pragma unroll
        for (int half = 0; half < 2; half++) {
            #pragma unroll
            for (int kb = 0; kb < 4; kb++) {
                int kr = kb * 16 + rl;
                bf16x8 kf = *(const bf16x8*)(
                    K_l + kr * 64 + (((lg + half * 4) ^ (kr & 7)) & 7) * 8);
                sacc[kb] = __builtin_amdgcn_mfma_f32_16x16x32_bf16(
                    qf[half], kf, sacc[kb], 0, 0, 0);
            }
        }

        #pragma unroll
        for (int kb = 0; kb < 4; kb++) sacc[kb] *= 0.125f;   // DH^-0.5

        float f[4], p[4][4];
        #pragma unroll
        for (int j = 0; j < 4; j++) {
            float t = fmaxf(fmaxf(sacc[0][j], sacc[1][j]),
                            fmaxf(sacc[2][j], sacc[3][j]));
            t = fmaxf(t, __shfl_xor(t, 1));
            t = fmaxf(t, __shfl_xor(t, 2));
            t = fmaxf(t, __shfl_xor(t, 4));
            t = fmaxf(t, __shfl_xor(t, 8));
            float nm = fmaxf(mrow[j], t);
            f[j] = __expf(mrow[j] - nm);    // exp(-inf)=0 on first tile
            mrow[j] = nm;
        }
        #pragma unroll
        for (int kb = 0; kb < 4; kb++)
            #pragma unroll
            for (int j = 0; j < 4; j++)
                p[kb][j] = __expf(sacc[kb][j] - mrow[j]);
        #pragma unroll
        for (int j = 0; j < 4; j++) {
            float s = (p[0][j] + p[1][j]) + (p[2][j] + p[3][j]);
            s += __shfl_xor(s, 1);
            s += __shfl_xor(s, 2);
            s += __shfl_xor(s, 4);
            s += __shfl_xor(s, 8);
            lrow[j] = lrow[j] * f[j] + s;
        }
        fx4 fv = {f[0], f[1], f[2], f[3]};
        #pragma unroll
        for (int db = 0; db < 4; db++) acc_o[db] *= fv;

        #pragma unroll
        for (int kb = 0; kb < 4; kb++) {
            #pragma unroll
            for (int j = 0; j < 4; j++) {
                int q16 = lg * 4 + j;
                int phys = ((kb * 2 + (rl >> 3)) ^ (q16 & 7)) & 7;
                Pw[q16 * 64 + phys * 8 + (rl & 7)] = f2bf(p[kb][j]);
            }
        }
        asm volatile("s_waitcnt lgkmcnt(0)" ::: "memory");

        #pragma unroll
        for (int half = 0; half < 2; half++) {
            bf16x8 pf = *(const bf16x8*)(
                Pw + rl * 64 + (((lg + half * 4) ^ (rl & 7)) & 7) * 8);
            #pragma unroll
            for (int db = 0; db < 4; db++) {
                int d = db * 16 + rl;
                bf16x8 vf = *(const bf16x8*)(
                    VT_l + d * 64 +
                    ((((lg + half * 4) ^ (d & 7)) ^ ((d >> 3) & 7)) & 7) * 8);
                acc_o[db] = __builtin_amdgcn_mfma_f32_16x16x32_bf16(
                    pf, vf, acc_o[db], 0, 0, 0);
            }
        }
    }

    float inv[4];
    #pragma unroll
    for (int j = 0; j < 4; j++) inv[j] = 1.0f / lrow[j];
    #pragma unroll
    for (int db = 0; db < 4; db++) {
        #pragma unroll
        for (int j = 0; j < 4; j++) {
            int row = qi * 64 + w * 16 + lg * 4 + j;
            out[(size_t)(b * TT + row) * INNER + h * DH + db * 16 + rl] =
                f2bf(acc_o[db][j] * inv[j]);
        }
    }
}

// ---------------------------------------------------------------------------
// Launch
// ---------------------------------------------------------------------------
extern "C" void kernel_launch(void* const* d_in, const int* in_sizes, int n_in,
                              void* d_out, int out_size, void* d_ws, size_t ws_size,
                              hipStream_t stream)
{
    const float* x     = (const float*)d_in[0];
    const float* c     = (const float*)d_in[1];
    const float* W_mod = (const float*)d_in[2];
    const float* b_mod = (const float*)d_in[3];
    const float* W_qkv = (const float*)d_in[4];
    const float* W_out = (const float*)d_in[5];
    const float* b_out = (const float*)d_in[6];
    const float* W1    = (const float*)d_in[7];
    const float* b1    = (const float*)d_in[8];
    const float* W2    = (const float*)d_in[9];
    const float* b2    = (const float*)d_in[10];
    float* out = (float*)d_out;

    const int M = BB * TT;   // 4096

    // workspace layout
    char* ws = (char*)d_ws;
    float* mod      = (float*)ws;                          // 98 KB (pad 128 KB)
    float* mod_part = (float*)(ws + 131072);               // 786 KB (pad to 1 MB)
    float* x1       = (float*)(ws + 1048576);              // 16 MB fp32
    unsigned short* bb = (unsigned short*)(ws + 1048576 + (size_t)M * DIM * 4);
    unsigned short* Wqkv_t = bb;  bb += (size_t)3 * INNER * DIM;
    unsigned short* Wout_t = bb;  bb += (size_t)DIM * INNER;
    unsigned short* W1_t   = bb;  bb += (size_t)MLP * DIM;
    unsigned short* W2_t   = bb;  bb += (size_t)DIM * MLP;
    unsigned short* xm     = bb;  bb += (size_t)M * DIM;
    unsigned short* qkvb   = bb;  bb += (size_t)M * 3 * INNER;
    unsigned short* attnb  = bb;  bb += (size_t)M * INNER;
    unsigned short* xm2    = bb;  bb += (size_t)M * DIM;
    unsigned short* hbuf   = bb;  bb += (size_t)M * MLP;
    // FF2 split-K partials (2 x 16MB fp32) overlay dead xm+qkvb (32MB)
    float* ff2part = (float*)xm;

    // 0. weight transpose+convert (single dispatch)
    wcvt_all<<<12288, 256, 0, stream>>>(W_qkv, W_out, W1, W2,
                                        Wqkv_t, Wout_t, W1_t, W2_t);

    // 1. modulation
    mod_partial<<<dim3(24, 8), 256, 0, stream>>>(c, W_mod, mod_part);
    mod_reduce<<<24, 256, 0, stream>>>(mod_part, b_mod, mod);
    // 2. LN1 + modulate -> bf16
    ln_mod_kernel<<<M, 256, 0, stream>>>(x, mod, OFF_SH_MSA, OFF_SC_MSA, xm);
    // 3. QKV GEMM -> bf16 [M, 3072]   grid 12x16 = 192
    bgemm256<0, 1><<<dim3(12, 16), 512, 0, stream>>>(
        xm, Wqkv_t, nullptr, nullptr, nullptr, 0, qkvb,
        M, 3 * INNER, DIM, DIM, DIM, 0, 0);
    // 4. MFMA flash attention -> bf16 [M, 1024]
    attn_mfma<<<BB * HEADS * (TT / 64), 256, 0, stream>>>(qkvb, attnb);
    // 5. out-proj + gated residual (fp32)   grid 4x16 = 64
    bgemm256<2, 0><<<dim3(4, 16), 512, 0, stream>>>(
        attnb, Wout_t, b_out, x, mod, OFF_G_MSA, x1,
        M, DIM, INNER, INNER, INNER, 0, 0);
    // 6. LN2 + modulate -> bf16
    ln_mod_kernel<<<M, 256, 0, stream>>>(x1, mod, OFF_SH_MLP, OFF_SC_MLP, xm2);
    // 7. FF1 + bias + exact GELU -> bf16 [M, 4096]   grid 16x16 = 256
    bgemm256<1, 1><<<dim3(16, 16), 512, 0, stream>>>(
        xm2, W1_t, b1, nullptr, nullptr, 0, hbuf,
        M, MLP, DIM, DIM, DIM, 0, 0);
    // 8a. FF2 split-K=2 -> fp32 partials   grid 4x16x2 = 128
    bgemm256<3, 0><<<dim3(4, 16, 2), 512, 0, stream>>>(
        hbuf, W2_t, nullptr, nullptr, nullptr, 0, ff2part,
        M, DIM, MLP / 2, MLP, MLP, MLP / 2, M * DIM);
    // 8b. FF2 finish: out = x1 + g_mlp * (b2 + p0 + p1)
    ff2_fin<<<M * DIM / 1024, 256, 0, stream>>>(ff2part, x1, mod, b2, out);
}